// Round 8
// baseline (510.777 us; speedup 1.0000x reference)
//
#include <hip/hip_runtime.h>
#include <hip/hip_bf16.h>

// ---------------------------------------------------------------------------
// QLenet forward, exact-math strategy (round-0 notes):
//   All fq() outputs are e5m2 grid values (<=3 significant bits). Products of
//   two grid values have <=6-bit mantissas; dot sums (<=400 terms, bounded
//   exponent span) are EXACT in f64 -> order-independent -> matches float64
//   numpy reference. Intermediates stored as bf16 (exact for grid values);
//   LDS tiles hold f32 (also exact), accumulation stays f64.
// Round 7 -> 8 (fusion round):
//   * bn1+fq+relu+pool fused into kconv2's staging (reads c1+mr1 directly);
//     kbnpool#1 and the p1 19MB write+read round-trip deleted.
//   * bn2+fq+relu+pool fused into kfc1's staging (reads c2+mr2);
//     kbnpool#2 and p2 round-trip deleted.
//   * Launches 11 -> 9. Conv kernels otherwise unchanged (r7 tiling).
//   Perf model note: v_fma_f64 empirically ~8cy/wave-instr (two kernels'
//   durations consistently 2x the 4cy model) -> conv2 floor ~100us.
// ---------------------------------------------------------------------------

#define BATCH 8192

// fq: round to FP(e5m2) nearest-even, subnormal granule 2^-16, clip +-57344.
// Normal path (|x| >= 2^-14): integer round-to-nearest-even of the f64
// mantissa to 2 bits; carry propagates into the exponent automatically.
__device__ __forceinline__ double fq_d(double x) {
    long long b = __double_as_longlong(x);
    long long ab = b & 0x7fffffffffffffffLL;
    if (ab == 0) return x;                       // +-0 preserved (ref: where(ax>0,...))
    double q;
    if (ab >= 0x3F10000000000000LL) {            // |x| >= 2^-14
        long long r = b + 0x0001FFFFFFFFFFFFLL + ((b >> 50) & 1LL);
        r &= 0xFFFC000000000000LL;               // clear low 50 mantissa bits
        q = __longlong_as_double(r);
        q = fmin(fmax(q, -57344.0), 57344.0);
    } else {                                     // subnormal grid: 2^-16
        q = rint(x * 65536.0) * 1.52587890625e-05;
    }
    return q;
}

__device__ __forceinline__ unsigned short bfbits(double q) {
    __hip_bfloat16 h = __float2bfloat16((float)q);   // exact for grid values
    return *(unsigned short*)&h;
}

// ---------------- merged prep: quantize conv weights, fc biases; transpose+
// quantize fc weights (padded). Flat index over all segments. ----------------
__global__ void kprep(const float* __restrict__ w1, const float* __restrict__ w2,
                      const float* __restrict__ fb1, const float* __restrict__ fb2,
                      const float* __restrict__ fb3, const float* __restrict__ fw1,
                      const float* __restrict__ fw2, const float* __restrict__ fw3,
                      float* __restrict__ qw1, float* __restrict__ qw2,
                      float* __restrict__ qfb1, float* __restrict__ qfb2,
                      float* __restrict__ qfb3, float* __restrict__ Wt1,
                      float* __restrict__ Wt2, float* __restrict__ Wt3) {
    int i = blockIdx.x * 256 + threadIdx.x;
    if (i < 150) { qw1[i] = (float)fq_d((double)w1[i]); return; }
    i -= 150;
    if (i < 2400) { qw2[i] = (float)fq_d((double)w2[i]); return; }
    i -= 2400;
    if (i < 120) { qfb1[i] = (float)fq_d((double)fb1[i]); return; }
    i -= 120;
    if (i < 84) { qfb2[i] = (float)fq_d((double)fb2[i]); return; }
    i -= 84;
    if (i < 10) { qfb3[i] = (float)fq_d((double)fb3[i]); return; }
    i -= 10;
    if (i < 51200) { int k = i / 128, o = i % 128;
        Wt1[i] = (o < 120) ? (float)fq_d((double)fw1[o * 400 + k]) : 0.0f; return; }
    i -= 51200;
    if (i < 15360) { int k = i / 128, o = i % 128;
        Wt2[i] = (o < 84) ? (float)fq_d((double)fw2[o * 120 + k]) : 0.0f; return; }
    i -= 15360;
    if (i < 1344) { int k = i / 16, o = i % 16;
        Wt3[i] = (o < 10) ? (float)fq_d((double)fw3[o * 84 + k]) : 0.0f; return; }
}
#define PREP_TOTAL (150 + 2400 + 120 + 84 + 10 + 51200 + 15360 + 1344)

// ---------------- conv1 + fq + fused BN stats ----------------
// [B,1,32,32] -> [B,6,28,28]. 3 images/block; task = 2x7 output tile with
// rotated-w row reuse. x tile f32, stride 33. Stats: per-task (s,s2) ->
// shared f64 atomics per channel -> 32-binned global atomics.
__global__ __launch_bounds__(256) void kconv1(const float* __restrict__ x,
        const float* __restrict__ qw, __hip_bfloat16* __restrict__ c1,
        int nimg_total, double* __restrict__ st1) {
    __shared__ float sxf[3 * 1056];   // 3 x (32 rows x 33) f32
    __shared__ double swd[152];
    __shared__ double sred[6][2];
    int t = threadIdx.x;
    int b0 = blockIdx.x * 3;
    int nimg = nimg_total - b0; if (nimg > 3) nimg = 3;
    for (int i = t; i < nimg * 1024; i += 256) {
        int img = i >> 10, idx = i & 1023;
        sxf[img * 1056 + (idx >> 5) * 33 + (idx & 31)] =
            (float)fq_d((double)x[(size_t)(b0 + img) * 1024 + idx]);
    }
    if (t < 150) swd[t] = (double)qw[t];
    if (t >= 192 && t < 204) ((double*)sred)[t - 192] = 0.0;
    __syncthreads();
    int ntask = nimg * 336;           // 6 co x 14 rowpairs x 4 colchunks
    for (int task = t; task < ntask; task += 256) {
        int img = task / 336; int rr = task % 336;
        int co = rr / 56; int rem = rr % 56;
        int i0 = (rem >> 2) * 2;      // 0,2,...,26
        int j0 = (rem & 3) * 7;       // 0,7,14,21
        const float* xb = &sxf[img * 1056];
        const double* wp = &swd[co * 25];
        double a0[7], a1[7];
        #pragma unroll
        for (int j = 0; j < 7; ++j) { a0[j] = 0.0; a1[j] = 0.0; }
        double wr[5], wq[5];
        #pragma unroll
        for (int u = 0; u < 6; ++u) {
            const float* xr = &xb[(i0 + u) * 33 + j0];
            double xv[11];
            #pragma unroll
            for (int k = 0; k < 11; ++k) xv[k] = (double)xr[k];
            if (u < 5) {
                #pragma unroll
                for (int tt = 0; tt < 5; ++tt) wr[tt] = wp[u * 5 + tt];
                #pragma unroll
                for (int j = 0; j < 7; ++j)
                    a0[j] = fma(xv[j], wr[0], fma(xv[j+1], wr[1], fma(xv[j+2], wr[2],
                            fma(xv[j+3], wr[3], fma(xv[j+4], wr[4], a0[j])))));
            }
            if (u >= 1) {
                #pragma unroll
                for (int j = 0; j < 7; ++j)
                    a1[j] = fma(xv[j], wq[0], fma(xv[j+1], wq[1], fma(xv[j+2], wq[2],
                            fma(xv[j+3], wq[3], fma(xv[j+4], wq[4], a1[j])))));
            }
            #pragma unroll
            for (int tt = 0; tt < 5; ++tt) wq[tt] = wr[tt];   // SSA rotate
        }
        size_t base = ((size_t)(b0 + img) * 6 + co) * 784 + (size_t)i0 * 28 + j0;
        double s = 0.0, s2 = 0.0;
        #pragma unroll
        for (int j = 0; j < 7; ++j) {
            double q0 = fq_d(a0[j]), q1 = fq_d(a1[j]);
            ((unsigned short*)c1)[base + j]      = bfbits(q0);
            ((unsigned short*)c1)[base + 28 + j] = bfbits(q1);
            s += q0 + q1; s2 += q0 * q0 + q1 * q1;
        }
        atomicAdd(&sred[co][0], s);
        atomicAdd(&sred[co][1], s2);
    }
    __syncthreads();
    if (t < 12) atomicAdd(&st1[t * 32 + (blockIdx.x & 31)], ((double*)sred)[t]);
}

// ---------------- finalize BN from 32-binned stats: m, rsqrt(v+eps) --------
__global__ void kfinal(const double* __restrict__ st, double* __restrict__ mr,
                       int C, double N) {
    int c = threadIdx.x;
    if (c < C) {
        double s = 0.0, s2 = 0.0;
        for (int b = 0; b < 32; ++b) { s += st[c * 64 + b]; s2 += st[c * 64 + 32 + b]; }
        double m = s / N;
        double v = s2 / N - m * m;
        mr[2 * c] = m;
        mr[2 * c + 1] = 1.0 / sqrt(v + 1e-5);
    }
}

// ---------------- conv2 (+fused bn1/fq/relu/pool staging) + fq + stats -----
// Reads c1 [B,6,28,28] + mr1; stages pooled [6][14][14] f32 tiles for 4
// images; computes [B,16,10,10] with 2x10 row-pair tiles (rotated-w reuse).
__global__ __launch_bounds__(320) void kconv2(const __hip_bfloat16* __restrict__ c1,
        const double* __restrict__ mr1, const float* __restrict__ g1,
        const float* __restrict__ be1, const float* __restrict__ qw,
        __hip_bfloat16* __restrict__ c2, double* __restrict__ st2) {
    __shared__ float sxf[4704];    // 4 x [6][14][14]
    __shared__ float swf[2400];    // [16][6][5][5]
    __shared__ double sred[16][2];
    __shared__ double sbn[6][4];   // m, r, g, b per bn1 channel
    int t = threadIdx.x;
    int b0 = blockIdx.x * 4;
    if (t < 6) {
        sbn[t][0] = mr1[2 * t]; sbn[t][1] = mr1[2 * t + 1];
        sbn[t][2] = (double)g1[t]; sbn[t][3] = (double)be1[t];
    }
    if (t >= 64 && t < 96) ((double*)sred)[t - 64] = 0.0;
    for (int i = t; i < 2400; i += 320) swf[i] = qw[i];
    __syncthreads();
    // fused bn1 + fq + relu + 2x2 pool staging
    for (int i = t; i < 4704; i += 320) {
        int img = i / 1176, k = i % 1176;
        int c = k / 196, rem = k % 196;
        int ph = rem / 14, pw = rem % 14;
        const __hip_bfloat16* src = c1 + (((size_t)(b0 + img) * 6 + c) * 28 + 2 * ph) * 28 + 2 * pw;
        double m = sbn[c][0], r = sbn[c][1], gg = sbn[c][2], bb = sbn[c][3];
        float best = 0.0f;
        #pragma unroll
        for (int dy = 0; dy < 2; ++dy) {
            #pragma unroll
            for (int dx = 0; dx < 2; ++dx) {
                double v = (double)__bfloat162float(src[dy * 28 + dx]);
                double q = fq_d(((v - m) * r) * gg + bb);
                best = fmaxf(best, (float)q);
            }
        }
        sxf[i] = best;
    }
    __syncthreads();
    int img = t / 80, r = t % 80;
    int co = r / 5, i0 = (r % 5) * 2;
    const float* xb = &sxf[img * 1176];
    const float* wb = &swf[co * 150];
    double a0[10], a1[10];
    #pragma unroll
    for (int j = 0; j < 10; ++j) { a0[j] = 0.0; a1[j] = 0.0; }
    double wr[5], wq[5];
    for (int ci = 0; ci < 6; ++ci) {
        #pragma unroll
        for (int u = 0; u < 6; ++u) {
            const float* xr = &xb[ci * 196 + (i0 + u) * 14];
            double xv[14];
            #pragma unroll
            for (int k = 0; k < 14; ++k) xv[k] = (double)xr[k];
            if (u < 5) {
                #pragma unroll
                for (int tt = 0; tt < 5; ++tt) wr[tt] = (double)wb[ci * 25 + u * 5 + tt];
                #pragma unroll
                for (int j = 0; j < 10; ++j)
                    a0[j] = fma(xv[j], wr[0], fma(xv[j+1], wr[1], fma(xv[j+2], wr[2],
                            fma(xv[j+3], wr[3], fma(xv[j+4], wr[4], a0[j])))));
            }
            if (u >= 1) {
                #pragma unroll
                for (int j = 0; j < 10; ++j)
                    a1[j] = fma(xv[j], wq[0], fma(xv[j+1], wq[1], fma(xv[j+2], wq[2],
                            fma(xv[j+3], wq[3], fma(xv[j+4], wq[4], a1[j])))));
            }
            #pragma unroll
            for (int tt = 0; tt < 5; ++tt) wq[tt] = wr[tt];   // SSA rotate
        }
    }
    size_t base = ((size_t)(b0 + img) * 16 + co) * 100 + (size_t)i0 * 10;
    double s = 0.0, s2 = 0.0;
    #pragma unroll
    for (int j = 0; j < 10; ++j) {
        double q0 = fq_d(a0[j]), q1 = fq_d(a1[j]);
        ((unsigned short*)c2)[base + j]      = bfbits(q0);
        ((unsigned short*)c2)[base + 10 + j] = bfbits(q1);
        s += q0 + q1; s2 += q0 * q0 + q1 * q1;
    }
    atomicAdd(&sred[co][0], s);
    atomicAdd(&sred[co][1], s2);
    __syncthreads();
    if (t < 32) atomicAdd(&st2[t * 32 + (blockIdx.x & 31)], ((double*)sred)[t]);
}

// ---------------- fc1 (+fused bn2/fq/relu/pool staging) ----------------
// Reads c2 [B,16,10,10] + mr2; stages pooled [16][5][5]=400 f64 rows for 16
// images; computes relu(fq(x @ Wt1 + b)).
__global__ __launch_bounds__(256) void kfc1(const __hip_bfloat16* __restrict__ c2,
        const double* __restrict__ mr2, const float* __restrict__ g2,
        const float* __restrict__ be2, const float* __restrict__ Wt,
        const float* __restrict__ qb, __hip_bfloat16* __restrict__ outb) {
    constexpr int IN = 400, OUT = 120, OUTP = 128, ROWS = 8, BT = 16;
    __shared__ double sx[BT][IN];
    __shared__ double sbn[16][4];
    int t = threadIdx.x;
    int b0 = blockIdx.x * BT;
    if (t < 16) {
        sbn[t][0] = mr2[2 * t]; sbn[t][1] = mr2[2 * t + 1];
        sbn[t][2] = (double)g2[t]; sbn[t][3] = (double)be2[t];
    }
    __syncthreads();
    for (int i = t; i < BT * IN; i += 256) {
        int r = i / IN, k = i % IN;
        int c = k / 25, rem = k % 25;
        int ph = rem / 5, pw = rem % 5;
        const __hip_bfloat16* src = c2 + (((size_t)(b0 + r) * 16 + c) * 10 + 2 * ph) * 10 + 2 * pw;
        double m = sbn[c][0], rr = sbn[c][1], gg = sbn[c][2], bb = sbn[c][3];
        double best = 0.0;
        #pragma unroll
        for (int dy = 0; dy < 2; ++dy) {
            #pragma unroll
            for (int dx = 0; dx < 2; ++dx) {
                double v = (double)__bfloat162float(src[dy * 10 + dx]);
                double q = fq_d(((v - m) * rr) * gg + bb);
                best = fmax(best, q);
            }
        }
        sx[r][k] = best;
    }
    __syncthreads();
    int o = t % OUTP;
    int g = t / OUTP;
    double acc[ROWS];
    double bias = (o < OUT) ? (double)qb[o] : 0.0;
    #pragma unroll
    for (int r = 0; r < ROWS; ++r) acc[r] = bias;
    #pragma unroll 4
    for (int k = 0; k < IN; ++k) {
        double w = (double)Wt[k * OUTP + o];   // coalesced, L2-resident
        #pragma unroll
        for (int r = 0; r < ROWS; ++r)
            acc[r] = fma(sx[g * ROWS + r][k], w, acc[r]);  // LDS broadcast reads
    }
    if (o < OUT) {
        #pragma unroll
        for (int r = 0; r < ROWS; ++r) {
            double q = fq_d(acc[r]);
            if (q < 0.0) q = 0.0;
            outb[(size_t)(b0 + g * ROWS + r) * OUT + o] = __float2bfloat16((float)q);
        }
    }
}

// ---------------- tiled FC: out = [relu?] fq( X @ Wt + qb ) ----------------
template<int IN, int OUT, int OUTP, int ROWS>
__global__ __launch_bounds__(256) void kfc(const __hip_bfloat16* __restrict__ X,
        const float* __restrict__ Wt, const float* __restrict__ qb,
        __hip_bfloat16* __restrict__ outb, float* __restrict__ outf, int do_relu) {
    constexpr int GROUPS = 256 / OUTP;
    constexpr int BT = ROWS * GROUPS;
    __shared__ double sx[BT][IN];
    int t = threadIdx.x;
    int b0 = blockIdx.x * BT;
    for (int i = t; i < BT * IN; i += 256) {
        int r = i / IN, k = i % IN;
        sx[r][k] = (double)__bfloat162float(X[(size_t)(b0 + r) * IN + k]);
    }
    __syncthreads();
    int o = t % OUTP;
    int g = t / OUTP;
    double acc[ROWS];
    double bias = (o < OUT) ? (double)qb[o] : 0.0;
    #pragma unroll
    for (int r = 0; r < ROWS; ++r) acc[r] = bias;
    #pragma unroll 4
    for (int k = 0; k < IN; ++k) {
        double w = (double)Wt[k * OUTP + o];
        #pragma unroll
        for (int r = 0; r < ROWS; ++r)
            acc[r] = fma(sx[g * ROWS + r][k], w, acc[r]);
    }
    if (o < OUT) {
        #pragma unroll
        for (int r = 0; r < ROWS; ++r) {
            double q = fq_d(acc[r]);
            if (do_relu && q < 0.0) q = 0.0;
            size_t b = (size_t)(b0 + g * ROWS + r);
            if (outf) outf[b * OUT + o] = (float)q;
            else      outb[b * OUT + o] = __float2bfloat16((float)q);
        }
    }
}

// ---------------------------------------------------------------------------
extern "C" void kernel_launch(void* const* d_in, const int* in_sizes, int n_in,
                              void* d_out, int out_size, void* d_ws, size_t ws_size,
                              hipStream_t stream) {
    const float* x   = (const float*)d_in[0];
    const float* w1  = (const float*)d_in[1];
    const float* g1  = (const float*)d_in[2];
    const float* be1 = (const float*)d_in[3];
    const float* w2  = (const float*)d_in[4];
    const float* g2  = (const float*)d_in[5];
    const float* be2 = (const float*)d_in[6];
    const float* fw1 = (const float*)d_in[7];
    const float* fb1 = (const float*)d_in[8];
    const float* fw2 = (const float*)d_in[9];
    const float* fb2 = (const float*)d_in[10];
    const float* fw3 = (const float*)d_in[11];
    const float* fb3 = (const float*)d_in[12];

    char* ws = (char*)d_ws;
    double* stats1 = (double*)(ws + 0);      // [6][2][32] dbl = 3072 B
    double* stats2 = (double*)(ws + 3072);   // [16][2][32] dbl = 8192 B (ends 11264)
    double* mr1    = (double*)(ws + 11264);  // 12 dbl
    double* mr2    = (double*)(ws + 11392);  // 32 dbl
    float* qw1  = (float*)(ws + 12288);      // 150
    float* qw2  = (float*)(ws + 13312);      // 2400 (ends 22912)
    float* qfb1 = (float*)(ws + 23040);      // 120
    float* qfb2 = (float*)(ws + 23552);      // 84
    float* qfb3 = (float*)(ws + 24064);      // 10
    float* Wt1  = (float*)(ws + 24576);      // 400*128 (ends 229376)
    float* Wt2  = (float*)(ws + 229376);     // 120*128 (ends 290816)
    float* Wt3  = (float*)(ws + 290816);     // 84*16   (ends 296192)
    // big buffers (aliased by liveness)
    __hip_bfloat16* bufA = (__hip_bfloat16*)(ws + 303104);    // c1 [B,6,28,28] (77 MB)
    __hip_bfloat16* bufB = (__hip_bfloat16*)(ws + 77373440);  // c2 [B,16,10,10] (26 MB)
    __hip_bfloat16* bufC = (__hip_bfloat16*)(ws + 303104);    // a1 [B,120] (aliases dead c1)
    __hip_bfloat16* bufD = (__hip_bfloat16*)(ws + 303104 + 2097152); // a2 [B,84]

    // zero the binned BN accumulators
    hipMemsetAsync(ws, 0, 11264, stream);

    kprep<<<(PREP_TOTAL + 255) / 256, 256, 0, stream>>>(
        w1, w2, fb1, fb2, fb3, fw1, fw2, fw3,
        qw1, qw2, qfb1, qfb2, qfb3, Wt1, Wt2, Wt3);

    // conv1 + fq + stats -> bufA (c1)
    kconv1<<<(BATCH + 2) / 3, 256, 0, stream>>>(x, qw1, bufA, BATCH, stats1);
    kfinal<<<1, 32, 0, stream>>>(stats1, mr1, 6, (double)BATCH * 784.0);
    // conv2 (fused bn1/pool staging) + fq + stats -> bufB (c2)
    kconv2<<<BATCH / 4, 320, 0, stream>>>(bufA, mr1, g1, be1, qw2, bufB, stats2);
    kfinal<<<1, 32, 0, stream>>>(stats2, mr2, 16, (double)BATCH * 100.0);
    // fc1 (fused bn2/pool staging, +relu): -> bufC [B,120]
    kfc1<<<BATCH / 16, 256, 0, stream>>>(bufB, mr2, g2, be2, Wt1, qfb1, bufC);
    // fc2 (+relu): [B,120] -> [B,84]
    kfc<120, 84, 128, 8><<<BATCH / 16, 256, 0, stream>>>(bufC, Wt2, qfb2, bufD, (float*)nullptr, 1);
    // fc3: [B,84] -> [B,10] float out
    kfc<84, 10, 16, 1><<<BATCH / 16, 256, 0, stream>>>(bufD, Wt3, qfb3, (__hip_bfloat16*)nullptr, (float*)d_out, 0);
}

// Round 9
// 436.449 us; speedup vs baseline: 1.1703x; 1.1703x over previous
//
#include <hip/hip_runtime.h>
#include <hip/hip_bf16.h>

// ---------------------------------------------------------------------------
// QLenet forward, exact-math strategy (round-0 notes):
//   All fq() outputs are e5m2 grid values (<=3 significant bits). Products of
//   two grid values have <=6-bit mantissas; dot sums (<=400 terms, bounded
//   exponent span) are EXACT in f64 -> order-independent -> matches float64
//   numpy reference. Intermediates stored as bf16 (exact for grid values);
//   LDS tiles hold f32 (also exact), accumulation stays f64.
// Round 8 -> 9:
//   * bn1-fusion into kconv2 REVERTED (it moved 77MB of c1 reads + 4x fq into
//     a 21%-occupancy prologue: kconv2 147->235us, FETCH 10->38MB/dispatch).
//     Standalone kpool1 restored.
//   * Monotone-fq trick in both pool paths: fq and the BN affine are monotone
//     (slope r*g), so max(relu(fq(bn(v_i)))) = max(0, fq(bn(v*))), v* =
//     max/min of raw values by slope sign. 1 fq per pooled output, not 4.
//     BN association ((v-m)*r)*g+b unchanged -> bit-identical.
//   * kfc1 keeps fused bn2+pool staging (that fusion was a win) + same trick.
// ---------------------------------------------------------------------------

#define BATCH 8192

// fq: round to FP(e5m2) nearest-even, subnormal granule 2^-16, clip +-57344.
// Normal path (|x| >= 2^-14): integer round-to-nearest-even of the f64
// mantissa to 2 bits; carry propagates into the exponent automatically.
__device__ __forceinline__ double fq_d(double x) {
    long long b = __double_as_longlong(x);
    long long ab = b & 0x7fffffffffffffffLL;
    if (ab == 0) return x;                       // +-0 preserved (ref: where(ax>0,...))
    double q;
    if (ab >= 0x3F10000000000000LL) {            // |x| >= 2^-14
        long long r = b + 0x0001FFFFFFFFFFFFLL + ((b >> 50) & 1LL);
        r &= 0xFFFC000000000000LL;               // clear low 50 mantissa bits
        q = __longlong_as_double(r);
        q = fmin(fmax(q, -57344.0), 57344.0);
    } else {                                     // subnormal grid: 2^-16
        q = rint(x * 65536.0) * 1.52587890625e-05;
    }
    return q;
}

__device__ __forceinline__ unsigned short bfbits(double q) {
    __hip_bfloat16 h = __float2bfloat16((float)q);   // exact for grid values
    return *(unsigned short*)&h;
}

// ---------------- merged prep: quantize conv weights, fc biases; transpose+
// quantize fc weights (padded). Flat index over all segments. ----------------
__global__ void kprep(const float* __restrict__ w1, const float* __restrict__ w2,
                      const float* __restrict__ fb1, const float* __restrict__ fb2,
                      const float* __restrict__ fb3, const float* __restrict__ fw1,
                      const float* __restrict__ fw2, const float* __restrict__ fw3,
                      float* __restrict__ qw1, float* __restrict__ qw2,
                      float* __restrict__ qfb1, float* __restrict__ qfb2,
                      float* __restrict__ qfb3, float* __restrict__ Wt1,
                      float* __restrict__ Wt2, float* __restrict__ Wt3) {
    int i = blockIdx.x * 256 + threadIdx.x;
    if (i < 150) { qw1[i] = (float)fq_d((double)w1[i]); return; }
    i -= 150;
    if (i < 2400) { qw2[i] = (float)fq_d((double)w2[i]); return; }
    i -= 2400;
    if (i < 120) { qfb1[i] = (float)fq_d((double)fb1[i]); return; }
    i -= 120;
    if (i < 84) { qfb2[i] = (float)fq_d((double)fb2[i]); return; }
    i -= 84;
    if (i < 10) { qfb3[i] = (float)fq_d((double)fb3[i]); return; }
    i -= 10;
    if (i < 51200) { int k = i / 128, o = i % 128;
        Wt1[i] = (o < 120) ? (float)fq_d((double)fw1[o * 400 + k]) : 0.0f; return; }
    i -= 51200;
    if (i < 15360) { int k = i / 128, o = i % 128;
        Wt2[i] = (o < 84) ? (float)fq_d((double)fw2[o * 120 + k]) : 0.0f; return; }
    i -= 15360;
    if (i < 1344) { int k = i / 16, o = i % 16;
        Wt3[i] = (o < 10) ? (float)fq_d((double)fw3[o * 84 + k]) : 0.0f; return; }
}
#define PREP_TOTAL (150 + 2400 + 120 + 84 + 10 + 51200 + 15360 + 1344)

// ---------------- conv1 + fq + fused BN stats ----------------
// [B,1,32,32] -> [B,6,28,28]. 3 images/block; task = 2x7 output tile with
// rotated-w row reuse. x tile f32, stride 33. Stats: per-task (s,s2) ->
// shared f64 atomics per channel -> 32-binned global atomics.
__global__ __launch_bounds__(256) void kconv1(const float* __restrict__ x,
        const float* __restrict__ qw, __hip_bfloat16* __restrict__ c1,
        int nimg_total, double* __restrict__ st1) {
    __shared__ float sxf[3 * 1056];   // 3 x (32 rows x 33) f32
    __shared__ double swd[152];
    __shared__ double sred[6][2];
    int t = threadIdx.x;
    int b0 = blockIdx.x * 3;
    int nimg = nimg_total - b0; if (nimg > 3) nimg = 3;
    for (int i = t; i < nimg * 1024; i += 256) {
        int img = i >> 10, idx = i & 1023;
        sxf[img * 1056 + (idx >> 5) * 33 + (idx & 31)] =
            (float)fq_d((double)x[(size_t)(b0 + img) * 1024 + idx]);
    }
    if (t < 150) swd[t] = (double)qw[t];
    if (t >= 192 && t < 204) ((double*)sred)[t - 192] = 0.0;
    __syncthreads();
    int ntask = nimg * 336;           // 6 co x 14 rowpairs x 4 colchunks
    for (int task = t; task < ntask; task += 256) {
        int img = task / 336; int rr = task % 336;
        int co = rr / 56; int rem = rr % 56;
        int i0 = (rem >> 2) * 2;      // 0,2,...,26
        int j0 = (rem & 3) * 7;       // 0,7,14,21
        const float* xb = &sxf[img * 1056];
        const double* wp = &swd[co * 25];
        double a0[7], a1[7];
        #pragma unroll
        for (int j = 0; j < 7; ++j) { a0[j] = 0.0; a1[j] = 0.0; }
        double wr[5], wq[5];
        #pragma unroll
        for (int u = 0; u < 6; ++u) {
            const float* xr = &sxf[img * 1056 + (i0 + u) * 33 + j0];
            double xv[11];
            #pragma unroll
            for (int k = 0; k < 11; ++k) xv[k] = (double)xr[k];
            if (u < 5) {
                #pragma unroll
                for (int tt = 0; tt < 5; ++tt) wr[tt] = wp[u * 5 + tt];
                #pragma unroll
                for (int j = 0; j < 7; ++j)
                    a0[j] = fma(xv[j], wr[0], fma(xv[j+1], wr[1], fma(xv[j+2], wr[2],
                            fma(xv[j+3], wr[3], fma(xv[j+4], wr[4], a0[j])))));
            }
            if (u >= 1) {
                #pragma unroll
                for (int j = 0; j < 7; ++j)
                    a1[j] = fma(xv[j], wq[0], fma(xv[j+1], wq[1], fma(xv[j+2], wq[2],
                            fma(xv[j+3], wq[3], fma(xv[j+4], wq[4], a1[j])))));
            }
            #pragma unroll
            for (int tt = 0; tt < 5; ++tt) wq[tt] = wr[tt];   // SSA rotate
        }
        size_t base = ((size_t)(b0 + img) * 6 + co) * 784 + (size_t)i0 * 28 + j0;
        double s = 0.0, s2 = 0.0;
        #pragma unroll
        for (int j = 0; j < 7; ++j) {
            double q0 = fq_d(a0[j]), q1 = fq_d(a1[j]);
            ((unsigned short*)c1)[base + j]      = bfbits(q0);
            ((unsigned short*)c1)[base + 28 + j] = bfbits(q1);
            s += q0 + q1; s2 += q0 * q0 + q1 * q1;
        }
        atomicAdd(&sred[co][0], s);
        atomicAdd(&sred[co][1], s2);
    }
    __syncthreads();
    if (t < 12) atomicAdd(&st1[t * 32 + (blockIdx.x & 31)], ((double*)sred)[t]);
}

// ---------------- finalize BN from 32-binned stats: m, rsqrt(v+eps) --------
__global__ void kfinal(const double* __restrict__ st, double* __restrict__ mr,
                       int C, double N) {
    int c = threadIdx.x;
    if (c < C) {
        double s = 0.0, s2 = 0.0;
        for (int b = 0; b < 32; ++b) { s += st[c * 64 + b]; s2 += st[c * 64 + 32 + b]; }
        double m = s / N;
        double v = s2 / N - m * m;
        mr[2 * c] = m;
        mr[2 * c + 1] = 1.0 / sqrt(v + 1e-5);
    }
}

// ---------------- bn1 + fq + relu + 2x2 pool (monotone single-fq) ----------
// c1 [B,6,28,28] -> p1 [B,6,14,14]. 2 pooled outputs per thread (b64 loads).
__global__ __launch_bounds__(256) void kpool1(const __hip_bfloat16* __restrict__ c1,
        const double* __restrict__ mr1, const float* __restrict__ g1,
        const float* __restrict__ be1, __hip_bfloat16* __restrict__ p1) {
    int idx = blockIdx.x * 256 + threadIdx.x;   // pair-task: B*6*14*7
    int pp = idx % 7;  int t1 = idx / 7;
    int ph = t1 % 14;  int t2 = t1 / 14;
    int c  = t2 % 6;   int b  = t2 / 6;
    double m = mr1[2 * c], r = mr1[2 * c + 1];
    double gg = (double)g1[c], bb = (double)be1[c];
    bool useMax = (r * gg) >= 0.0;              // selection only, not arithmetic
    const __hip_bfloat16* src = c1 + (((size_t)b * 6 + c) * 28 + 2 * ph) * 28 + 4 * pp;
    ushort4 u0 = *(const ushort4*)src;          // row 2ph,   cols 4pp..4pp+3
    ushort4 u1 = *(const ushort4*)(src + 28);   // row 2ph+1
    float f0 = __bfloat162float(*(__hip_bfloat16*)&u0.x), f1 = __bfloat162float(*(__hip_bfloat16*)&u0.y);
    float f2 = __bfloat162float(*(__hip_bfloat16*)&u0.z), f3 = __bfloat162float(*(__hip_bfloat16*)&u0.w);
    float f4 = __bfloat162float(*(__hip_bfloat16*)&u1.x), f5 = __bfloat162float(*(__hip_bfloat16*)&u1.y);
    float f6 = __bfloat162float(*(__hip_bfloat16*)&u1.z), f7 = __bfloat162float(*(__hip_bfloat16*)&u1.w);
    float va = useMax ? fmaxf(fmaxf(f0, f1), fmaxf(f4, f5))
                      : fminf(fminf(f0, f1), fminf(f4, f5));
    float vb = useMax ? fmaxf(fmaxf(f2, f3), fmaxf(f6, f7))
                      : fminf(fminf(f2, f3), fminf(f6, f7));
    double qa = fq_d((((double)va - m) * r) * gg + bb);   // same association as ever
    double qb = fq_d((((double)vb - m) * r) * gg + bb);
    qa = fmax(qa, 0.0); qb = fmax(qb, 0.0);
    ushort2 pk; pk.x = bfbits(qa); pk.y = bfbits(qb);
    *(ushort2*)&p1[((size_t)b * 6 + c) * 196 + ph * 14 + 2 * pp] = pk;
}

// ---------------- conv2 + fq + fused BN stats (reads pooled p1) ------------
// [B,6,14,14] -> [B,16,10,10]. 4 images/block, 320 threads; task = 2x10
// row-pair tile with rotated-w row reuse. x,w in LDS as f32 (exact), f64 acc.
__global__ __launch_bounds__(320) void kconv2(const __hip_bfloat16* __restrict__ p1,
        const float* __restrict__ qw, __hip_bfloat16* __restrict__ c2,
        double* __restrict__ st2) {
    __shared__ float sxf[4704];    // 4 x [6][14][14]
    __shared__ float swf[2400];    // [16][6][5][5]
    __shared__ double sred[16][2];
    int t = threadIdx.x;
    int b0 = blockIdx.x * 4;
    for (int i = t; i < 4704; i += 320) sxf[i] = __bfloat162float(p1[(size_t)b0 * 1176 + i]);
    for (int i = t; i < 2400; i += 320) swf[i] = qw[i];
    if (t < 32) ((double*)sred)[t] = 0.0;
    __syncthreads();
    int img = t / 80, r = t % 80;
    int co = r / 5, i0 = (r % 5) * 2;
    const float* xb = &sxf[img * 1176];
    const float* wb = &swf[co * 150];
    double a0[10], a1[10];
    #pragma unroll
    for (int j = 0; j < 10; ++j) { a0[j] = 0.0; a1[j] = 0.0; }
    double wr[5], wq[5];
    for (int ci = 0; ci < 6; ++ci) {
        #pragma unroll
        for (int u = 0; u < 6; ++u) {
            const float* xr = &xb[ci * 196 + (i0 + u) * 14];
            double xv[14];
            #pragma unroll
            for (int k = 0; k < 14; ++k) xv[k] = (double)xr[k];
            if (u < 5) {
                #pragma unroll
                for (int tt = 0; tt < 5; ++tt) wr[tt] = (double)wb[ci * 25 + u * 5 + tt];
                #pragma unroll
                for (int j = 0; j < 10; ++j)
                    a0[j] = fma(xv[j], wr[0], fma(xv[j+1], wr[1], fma(xv[j+2], wr[2],
                            fma(xv[j+3], wr[3], fma(xv[j+4], wr[4], a0[j])))));
            }
            if (u >= 1) {
                #pragma unroll
                for (int j = 0; j < 10; ++j)
                    a1[j] = fma(xv[j], wq[0], fma(xv[j+1], wq[1], fma(xv[j+2], wq[2],
                            fma(xv[j+3], wq[3], fma(xv[j+4], wq[4], a1[j])))));
            }
            #pragma unroll
            for (int tt = 0; tt < 5; ++tt) wq[tt] = wr[tt];   // SSA rotate
        }
    }
    size_t base = ((size_t)(b0 + img) * 16 + co) * 100 + (size_t)i0 * 10;
    double s = 0.0, s2 = 0.0;
    #pragma unroll
    for (int j = 0; j < 10; ++j) {
        double q0 = fq_d(a0[j]), q1 = fq_d(a1[j]);
        ((unsigned short*)c2)[base + j]      = bfbits(q0);
        ((unsigned short*)c2)[base + 10 + j] = bfbits(q1);
        s += q0 + q1; s2 += q0 * q0 + q1 * q1;
    }
    atomicAdd(&sred[co][0], s);
    atomicAdd(&sred[co][1], s2);
    __syncthreads();
    if (t < 32) atomicAdd(&st2[t * 32 + (blockIdx.x & 31)], ((double*)sred)[t]);
}

// ---------------- fc1 (+fused bn2/fq/relu/pool staging, single-fq) ---------
__global__ __launch_bounds__(256) void kfc1(const __hip_bfloat16* __restrict__ c2,
        const double* __restrict__ mr2, const float* __restrict__ g2,
        const float* __restrict__ be2, const float* __restrict__ Wt,
        const float* __restrict__ qb, __hip_bfloat16* __restrict__ outb) {
    constexpr int IN = 400, OUT = 120, OUTP = 128, ROWS = 8, BT = 16;
    __shared__ double sx[BT][IN];
    __shared__ double sbn[16][4];
    int t = threadIdx.x;
    int b0 = blockIdx.x * BT;
    if (t < 16) {
        sbn[t][0] = mr2[2 * t]; sbn[t][1] = mr2[2 * t + 1];
        sbn[t][2] = (double)g2[t]; sbn[t][3] = (double)be2[t];
    }
    __syncthreads();
    for (int i = t; i < BT * IN; i += 256) {
        int r = i / IN, k = i % IN;
        int c = k / 25, rem = k % 25;
        int ph = rem / 5, pw = rem % 5;
        const __hip_bfloat16* src = c2 + (((size_t)(b0 + r) * 16 + c) * 10 + 2 * ph) * 10 + 2 * pw;
        double m = sbn[c][0], rr = sbn[c][1], gg = sbn[c][2], bb = sbn[c][3];
        float f0 = __bfloat162float(src[0]),  f1 = __bfloat162float(src[1]);
        float f2 = __bfloat162float(src[10]), f3 = __bfloat162float(src[11]);
        bool useMax = (rr * gg) >= 0.0;
        float v = useMax ? fmaxf(fmaxf(f0, f1), fmaxf(f2, f3))
                         : fminf(fminf(f0, f1), fminf(f2, f3));
        double q = fq_d((((double)v - m) * rr) * gg + bb);
        sx[r][k] = fmax(q, 0.0);
    }
    __syncthreads();
    int o = t % OUTP;
    int g = t / OUTP;
    double acc[ROWS];
    double bias = (o < OUT) ? (double)qb[o] : 0.0;
    #pragma unroll
    for (int r = 0; r < ROWS; ++r) acc[r] = bias;
    #pragma unroll 4
    for (int k = 0; k < IN; ++k) {
        double w = (double)Wt[k * OUTP + o];   // coalesced, L2-resident
        #pragma unroll
        for (int r = 0; r < ROWS; ++r)
            acc[r] = fma(sx[g * ROWS + r][k], w, acc[r]);  // LDS broadcast reads
    }
    if (o < OUT) {
        #pragma unroll
        for (int r = 0; r < ROWS; ++r) {
            double q = fq_d(acc[r]);
            if (q < 0.0) q = 0.0;
            outb[(size_t)(b0 + g * ROWS + r) * OUT + o] = __float2bfloat16((float)q);
        }
    }
}

// ---------------- tiled FC: out = [relu?] fq( X @ Wt + qb ) ----------------
template<int IN, int OUT, int OUTP, int ROWS>
__global__ __launch_bounds__(256) void kfc(const __hip_bfloat16* __restrict__ X,
        const float* __restrict__ Wt, const float* __restrict__ qb,
        __hip_bfloat16* __restrict__ outb, float* __restrict__ outf, int do_relu) {
    constexpr int GROUPS = 256 / OUTP;
    constexpr int BT = ROWS * GROUPS;
    __shared__ double sx[BT][IN];
    int t = threadIdx.x;
    int b0 = blockIdx.x * BT;
    for (int i = t; i < BT * IN; i += 256) {
        int r = i / IN, k = i % IN;
        sx[r][k] = (double)__bfloat162float(X[(size_t)(b0 + r) * IN + k]);
    }
    __syncthreads();
    int o = t % OUTP;
    int g = t / OUTP;
    double acc[ROWS];
    double bias = (o < OUT) ? (double)qb[o] : 0.0;
    #pragma unroll
    for (int r = 0; r < ROWS; ++r) acc[r] = bias;
    #pragma unroll 4
    for (int k = 0; k < IN; ++k) {
        double w = (double)Wt[k * OUTP + o];
        #pragma unroll
        for (int r = 0; r < ROWS; ++r)
            acc[r] = fma(sx[g * ROWS + r][k], w, acc[r]);
    }
    if (o < OUT) {
        #pragma unroll
        for (int r = 0; r < ROWS; ++r) {
            double q = fq_d(acc[r]);
            if (do_relu && q < 0.0) q = 0.0;
            size_t b = (size_t)(b0 + g * ROWS + r);
            if (outf) outf[b * OUT + o] = (float)q;
            else      outb[b * OUT + o] = __float2bfloat16((float)q);
        }
    }
}

// ---------------------------------------------------------------------------
extern "C" void kernel_launch(void* const* d_in, const int* in_sizes, int n_in,
                              void* d_out, int out_size, void* d_ws, size_t ws_size,
                              hipStream_t stream) {
    const float* x   = (const float*)d_in[0];
    const float* w1  = (const float*)d_in[1];
    const float* g1  = (const float*)d_in[2];
    const float* be1 = (const float*)d_in[3];
    const float* w2  = (const float*)d_in[4];
    const float* g2  = (const float*)d_in[5];
    const float* be2 = (const float*)d_in[6];
    const float* fw1 = (const float*)d_in[7];
    const float* fb1 = (const float*)d_in[8];
    const float* fw2 = (const float*)d_in[9];
    const float* fb2 = (const float*)d_in[10];
    const float* fw3 = (const float*)d_in[11];
    const float* fb3 = (const float*)d_in[12];

    char* ws = (char*)d_ws;
    double* stats1 = (double*)(ws + 0);      // [6][2][32] dbl = 3072 B
    double* stats2 = (double*)(ws + 3072);   // [16][2][32] dbl = 8192 B (ends 11264)
    double* mr1    = (double*)(ws + 11264);  // 12 dbl
    double* mr2    = (double*)(ws + 11392);  // 32 dbl
    float* qw1  = (float*)(ws + 12288);      // 150
    float* qw2  = (float*)(ws + 13312);      // 2400 (ends 22912)
    float* qfb1 = (float*)(ws + 23040);      // 120
    float* qfb2 = (float*)(ws + 23552);      // 84
    float* qfb3 = (float*)(ws + 24064);      // 10
    float* Wt1  = (float*)(ws + 24576);      // 400*128 (ends 229376)
    float* Wt2  = (float*)(ws + 229376);     // 120*128 (ends 290816)
    float* Wt3  = (float*)(ws + 290816);     // 84*16   (ends 296192)
    // big buffers (aliased by liveness; peak ws usage ~96.7 MB)
    __hip_bfloat16* c1 = (__hip_bfloat16*)(ws + 303104);      // [B,6,28,28] 77.1 MB
    __hip_bfloat16* p1 = (__hip_bfloat16*)(ws + 77373440);    // [B,6,14,14] 19.3 MB
    __hip_bfloat16* c2 = (__hip_bfloat16*)(ws + 303104);      // [B,16,10,10] 26.2 MB (c1 dead)
    __hip_bfloat16* a1 = (__hip_bfloat16*)(ws + 303104 + 26214400); // [B,120] 2.0 MB
    __hip_bfloat16* a2 = (__hip_bfloat16*)(ws + 303104 + 28180480); // [B,84] 1.4 MB

    // zero the binned BN accumulators
    hipMemsetAsync(ws, 0, 11264, stream);

    kprep<<<(PREP_TOTAL + 255) / 256, 256, 0, stream>>>(
        w1, w2, fb1, fb2, fb3, fw1, fw2, fw3,
        qw1, qw2, qfb1, qfb2, qfb3, Wt1, Wt2, Wt3);

    // conv1 + fq + stats -> c1
    kconv1<<<(BATCH + 2) / 3, 256, 0, stream>>>(x, qw1, c1, BATCH, stats1);
    kfinal<<<1, 32, 0, stream>>>(stats1, mr1, 6, (double)BATCH * 784.0);
    // bn1 + fq + relu + pool (monotone single-fq) -> p1
    kpool1<<<BATCH * 6 * 14 * 7 / 256, 256, 0, stream>>>(c1, mr1, g1, be1, p1);
    // conv2 + fq + stats -> c2 (aliases dead c1)
    kconv2<<<BATCH / 4, 320, 0, stream>>>(p1, qw2, c2, stats2);
    kfinal<<<1, 32, 0, stream>>>(stats2, mr2, 16, (double)BATCH * 100.0);
    // fc1 (fused bn2/pool staging, +relu) -> a1 [B,120]
    kfc1<<<BATCH / 16, 256, 0, stream>>>(c2, mr2, g2, be2, Wt1, qfb1, a1);
    // fc2 (+relu): [B,120] -> [B,84]
    kfc<120, 84, 128, 8><<<BATCH / 16, 256, 0, stream>>>(a1, Wt2, qfb2, a2, (float*)nullptr, 1);
    // fc3: [B,84] -> [B,10] float out
    kfc<84, 10, 16, 1><<<BATCH / 16, 256, 0, stream>>>(a2, Wt3, qfb3, (__hip_bfloat16*)nullptr, (float*)d_out, 0);
}